// Round 2
// baseline (4173.895 us; speedup 1.0000x reference)
//
#include <hip/hip_runtime.h>
#include <hip/hip_bf16.h>
#include <math.h>

// Problem constants
#define NB 256   // graphs
#define NN 2048  // nodes
#define NR 64    // roots
#define ND 64    // embed dim
#define NT 8     // node types
// layer widths: KD = 128 (K*D), H2 = 128 (2*D)

// ---------------------------------------------------------------------------
// Pre-kernel: transpose weights to [type][out][in] and convert to bf16 (RNE).
//   w1t[t][j][i]  = bf16( W1[t][i][j] )   (128x128 per type)
//   w2t[t][d][jj] = bf16( W2[t][jj][d] )  (64x128 per type)
// Runs every launch (d_ws is re-poisoned before each timed call).
// ---------------------------------------------------------------------------
__global__ void convert_weights(const float* __restrict__ W1,
                                const float* __restrict__ W2,
                                unsigned short* __restrict__ w1t,
                                unsigned short* __restrict__ w2t) {
    int g = blockIdx.x * 256 + threadIdx.x;
    if (g < NT * 128 * 128) {
        int t = g >> 14, r = g & 16383, j = r >> 7, i = r & 127;
        unsigned u = __float_as_uint(W1[(t * 128 + i) * 128 + j]);
        w1t[g] = (unsigned short)((u + 0x7fffu + ((u >> 16) & 1u)) >> 16);
    }
    if (g < NT * 64 * 128) {
        int t = g >> 13, r = g & 8191, d = r >> 7, jj = r & 127;
        unsigned u = __float_as_uint(W2[(t * 128 + jj) * 64 + d]);
        w2t[g] = (unsigned short)((u + 0x7fffu + ((u >> 16) & 1u)) >> 16);
    }
}

struct Wreg {
    uint4 w1[8];   // 64 bf16: W1T row (j), this thread's half (64 inputs)
    uint4 w2[4];   // 32 bf16: W2T row (d), this wave's quarter (32 inputs)
    float b1v, b2v;
};

__device__ __forceinline__ float bf_lo(unsigned u) { return __uint_as_float(u << 16); }
__device__ __forceinline__ float bf_hi(unsigned u) { return __uint_as_float(u & 0xffff0000u); }

// ---------------------------------------------------------------------------
// Main kernel: one block (256 threads, 4 waves) per graph.
// Layer1: output j = tid>>1, i-half = tid&1  -> reduce via __shfl_xor(.,1).
//         Wave w produces exactly hs[32w..32w+31] -> layer2 stays intra-wave.
// Layer2: output d = tid&63, jj-quarter q = tid>>6 (== wave id); hs values
//         fetched by __shfl broadcast from own wave; 4-way partial reduce
//         through LDS (the only cross-wave exchange -> 2 barriers/node).
// Weights + parents for node pos+1 are prefetched during node pos.
// ---------------------------------------------------------------------------
__global__ __launch_bounds__(256, 1)
void dag_encoder_kernel(const float* __restrict__ roots,   // [B,R,D]
                        const float* __restrict__ b1,      // [T,128]
                        const float* __restrict__ b2,      // [T,64]
                        const int*   __restrict__ idxs,    // [B,N,2]
                        const int*   __restrict__ types,   // [B,N]
                        float* __restrict__ out,           // [B,N,D]
                        const unsigned short* __restrict__ w1t,
                        const unsigned short* __restrict__ w2t)
{
    __shared__ __align__(16) float xs[128];   // concat(parent0, parent1)
    __shared__ float part[256];               // layer2 partials
    __shared__ int   ltyp[NN];                // 8 KB
    __shared__ int   lidx[2 * NN];            // 16 KB

    const int b   = blockIdx.x;
    const int tid = threadIdx.x;
    float* buf = out + (size_t)b * NN * ND;

    // ---- stage roots into buf, types/idx into LDS ----
    {
        const float4* r4 = (const float4*)(roots + (size_t)b * NR * ND);
        float4* o4 = (float4*)buf;
        for (int i = tid; i < NR * ND / 4; i += 256) o4[i] = r4[i];
        const int4* si = (const int4*)(idxs + (size_t)b * NN * 2);
        int4* di = (int4*)lidx;
        for (int i = tid; i < NN * 2 / 4; i += 256) di[i] = si[i];
        const int4* st = (const int4*)(types + (size_t)b * NN);
        int4* dt = (int4*)ltyp;
        for (int i = tid; i < NN / 4; i += 256) dt[i] = st[i];
    }
    __syncthreads();

    const int j    = tid >> 1;   // layer1 output index (0..127)
    const int half = tid & 1;    // layer1 input half
    const int d    = tid & 63;   // layer2 output index
    const int q    = tid >> 6;   // wave id == layer2 input quarter

    Wreg A, Bw;

    auto prefetchW = [&](Wreg& W, int typ) {
        const uint4* p1 = (const uint4*)(w1t + ((typ * 128 + j) * 128 + half * 64));
        #pragma unroll
        for (int k = 0; k < 8; ++k) W.w1[k] = p1[k];
        const uint4* p2 = (const uint4*)(w2t + ((typ * 64 + d) * 128 + q * 32));
        #pragma unroll
        for (int k = 0; k < 4; ++k) W.w2[k] = p2[k];
        W.b1v = b1[typ * 128 + j];
        W.b2v = b2[typ * 64 + d];
    };

    // ---- prime node NR ----
    if (tid < 128) {
        int p = lidx[2 * NR + (tid >> 6)];
        xs[tid] = buf[p * ND + d];
    }
    prefetchW(A, ltyp[NR]);
    __syncthreads();

    auto step = [&](int pos, const Wreg& Wc, Wreg& Wn) {
        const int posn = (pos + 1 < NN) ? pos + 1 : NN - 1;
        // ---- prefetch next node's weights + parents (issued early) ----
        prefetchW(Wn, ltyp[posn]);
        int pn = -1; float xpn = 0.f;
        if (tid < 128) {
            pn  = lidx[2 * posn + (tid >> 6)];
            xpn = buf[(size_t)pn * ND + d];   // stale only if pn == pos (fixed up)
        }
        // ---- layer 1: 64-FMA partial, 4 accumulators ----
        const float4* xs4 = (const float4*)(xs + half * 64);
        float a0 = 0.f, a1 = 0.f, a2 = 0.f, a3 = 0.f;
        #pragma unroll
        for (int k = 0; k < 8; ++k) {
            float4 x0 = xs4[2 * k], x1 = xs4[2 * k + 1];
            uint4 u = Wc.w1[k];
            a0 += bf_lo(u.x) * x0.x;  a1 += bf_hi(u.x) * x0.y;
            a2 += bf_lo(u.y) * x0.z;  a3 += bf_hi(u.y) * x0.w;
            a0 += bf_lo(u.z) * x1.x;  a1 += bf_hi(u.z) * x1.y;
            a2 += bf_lo(u.w) * x1.z;  a3 += bf_hi(u.w) * x1.w;
        }
        float acc = (a0 + a1) + (a2 + a3);
        acc += __shfl_xor(acc, 1, 64);          // pair-reduce: full dot for j
        float v1 = acc + Wc.b1v;
        float g  = 0.5f * v1 * (1.0f + erff(v1 * 0.70710678118654752f));

        // ---- layer 2: hs broadcast via intra-wave shfl ----
        float c0 = 0.f, c1 = 0.f;
        #pragma unroll
        for (int k = 0; k < 4; ++k) {
            uint4 u = Wc.w2[k];
            float h0 = __shfl(g, 16 * k + 0, 64),  h1 = __shfl(g, 16 * k + 2, 64);
            float h2 = __shfl(g, 16 * k + 4, 64),  h3 = __shfl(g, 16 * k + 6, 64);
            float h4 = __shfl(g, 16 * k + 8, 64),  h5 = __shfl(g, 16 * k + 10, 64);
            float h6 = __shfl(g, 16 * k + 12, 64), h7 = __shfl(g, 16 * k + 14, 64);
            c0 += bf_lo(u.x) * h0;  c1 += bf_hi(u.x) * h1;
            c0 += bf_lo(u.y) * h2;  c1 += bf_hi(u.y) * h3;
            c0 += bf_lo(u.z) * h4;  c1 += bf_hi(u.z) * h5;
            c0 += bf_lo(u.w) * h6;  c1 += bf_hi(u.w) * h7;
        }
        part[tid] = c0 + c1;
        __syncthreads();                                   // barrier 1
        float v = ((part[d] + part[d + 64]) + (part[d + 128] + part[d + 192])) + Wc.b2v;
        if (tid < 64)  buf[(size_t)pos * ND + d] = v;      // node output
        if (tid < 128) xs[tid] = (pn == pos) ? v : xpn;    // next node's input
        __syncthreads();                                   // barrier 2
    };

    for (int pos = NR; pos < NN; pos += 2) {   // NN-NR = 1984, even
        step(pos,     A,  Bw);
        step(pos + 1, Bw, A);
    }
}

extern "C" void kernel_launch(void* const* d_in, const int* in_sizes, int n_in,
                              void* d_out, int out_size, void* d_ws, size_t ws_size,
                              hipStream_t stream) {
    const float* roots = (const float*)d_in[0];   // [B,R,D]
    const float* W1    = (const float*)d_in[1];   // [T,128,128]
    const float* b1    = (const float*)d_in[2];   // [T,128]
    const float* W2    = (const float*)d_in[3];   // [T,128,64]
    const float* b2    = (const float*)d_in[4];   // [T,64]
    const int*   idxs  = (const int*)d_in[5];     // [B,N,2]
    const int*   types = (const int*)d_in[6];     // [B,N]
    float*       outp  = (float*)d_out;           // [B,N,D]

    unsigned short* w1t = (unsigned short*)d_ws;             // 256 KB
    unsigned short* w2t = w1t + NT * 128 * 128;              // +128 KB  (total 384 KB of ws)

    convert_weights<<<dim3(512), dim3(256), 0, stream>>>(W1, W2, w1t, w2t);
    dag_encoder_kernel<<<dim3(NB), dim3(256), 0, stream>>>(
        roots, b1, b2, idxs, types, outp, w1t, w2t);
}

// Round 3
// 1060.723 us; speedup vs baseline: 3.9350x; 3.9350x over previous
//
#include <hip/hip_runtime.h>
#include <hip/hip_bf16.h>
#include <math.h>

// Problem constants
#define NB 256   // graphs
#define NN 2048  // nodes
#define NR 64    // roots
#define ND 64    // embed dim
#define NT 8     // node types
// KD = 128, H2 = 128

typedef __attribute__((ext_vector_type(8))) short short8;
typedef __attribute__((ext_vector_type(4))) float f32x4;

__device__ __forceinline__ unsigned short f2bf(float f) {
    unsigned u = __float_as_uint(f);
    return (unsigned short)((u + 0x7fffu + ((u >> 16) & 1u)) >> 16);
}

// ---------------------------------------------------------------------------
// Pre-kernel: transpose weights to [type][out][in] bf16 (RNE).
//   w1t[t][j][i]  = bf16( W1[t][i][j] )   (128x128 per type)
//   w2t[t][d][jj] = bf16( W2[t][jj][d] )  (64x128 per type)
// ---------------------------------------------------------------------------
__global__ void convert_weights(const float* __restrict__ W1,
                                const float* __restrict__ W2,
                                unsigned short* __restrict__ w1t,
                                unsigned short* __restrict__ w2t) {
    int g = blockIdx.x * 256 + threadIdx.x;
    if (g < NT * 128 * 128) {
        int t = g >> 14, r = g & 16383, j = r >> 7, i = r & 127;
        w1t[g] = f2bf(W1[(t * 128 + i) * 128 + j]);
    }
    if (g < NT * 64 * 128) {
        int t = g >> 13, r = g & 8191, d = r >> 7, jj = r & 127;
        w2t[g] = f2bf(W2[(t * 128 + jj) * 64 + d]);
    }
}

// ---------------------------------------------------------------------------
// Main kernel: one block (256 thr, 4 waves) per graph.
// Phase 1: depth relaxation (LDS), counting-sort nodes by (level,type).
// Phase 2: per level, per type: 16-node tiles through MFMA 16x16x32 bf16.
//   layer1: C1[16,128] = X[16,128] * W1  -> +b1 -> GELU -> hs (LDS, bf16)
//   layer2: C2[16,64]  = hs * W2         -> +b2 -> scatter to buf
// Fragment mappings (m89/m120-verified):
//   A[m=lane&15][k=(lane>>4)*8+j], B[k=(lane>>4)*8+j][n=lane&15],
//   D[row=(lane>>4)*4+reg][col=lane&15]
// ---------------------------------------------------------------------------
__global__ __launch_bounds__(256, 1)
void dag_encoder_kernel(const float* __restrict__ roots,
                        const float* __restrict__ b1,
                        const float* __restrict__ b2,
                        const int*   __restrict__ idxs,
                        const int*   __restrict__ types,
                        float* __restrict__ out,
                        const unsigned short* __restrict__ w1t,
                        const unsigned short* __restrict__ w2t)
{
    __shared__ unsigned int   depth[NN];      // 8 KB
    __shared__ unsigned short keys[NN];       // 4 KB
    __shared__ unsigned int   scanA[2049];    // 8.2 KB  (final: exclusive offsets)
    __shared__ unsigned int   scanB[2049];    // 8.2 KB  (scratch, then cursors)
    __shared__ unsigned short list[NN];       // 4 KB    (nodes sorted by key)
    __shared__ __align__(16) unsigned short xs[4][16][136];  // 17.4 KB
    __shared__ __align__(16) unsigned short hs[4][16][136];  // 17.4 KB
    __shared__ int s_changed, s_maxd;

    const int b   = blockIdx.x;
    const int tid = threadIdx.x;
    float* gbuf = out + (size_t)b * NN * ND;
    const int2* gidx = (const int2*)(idxs + (size_t)b * NN * 2);
    const int*  gtyp = types + (size_t)b * NN;

    // ---- roots -> buf ----
    {
        const float4* r4 = (const float4*)(roots + (size_t)b * NR * ND);
        float4* o4 = (float4*)gbuf;
        for (int i = tid; i < NR * ND / 4; i += 256) o4[i] = r4[i];
    }

    // ---- depth init ----
    for (int i = tid; i < NN; i += 256) depth[i] = (i < NR) ? 0u : 0xFFFFFFFFu;
    if (tid == 0) { s_maxd = 0; }
    __syncthreads();

    // ---- relaxation: in-order chunk sweeps until fixed point ----
    for (int sweep = 0; sweep < 300; ++sweep) {
        if (tid == 0) s_changed = 0;
        __syncthreads();
        #pragma unroll
        for (int c = 0; c < NN / 256; ++c) {
            int n = c * 256 + tid;
            if (n >= NR && depth[n] == 0xFFFFFFFFu) {
                int2 p = gidx[n];
                unsigned d0 = depth[p.x], d1 = depth[p.y];
                if (d0 != 0xFFFFFFFFu && d1 != 0xFFFFFFFFu) {
                    depth[n] = 1u + (d0 > d1 ? d0 : d1);
                    s_changed = 1;
                }
            }
            __syncthreads();
        }
        bool done = (s_changed == 0);
        __syncthreads();
        if (done) break;
    }

    // ---- max depth ----
    {
        unsigned m = 0;
        for (int i = tid; i < NN; i += 256) { unsigned d = depth[i]; if (d > m) m = d; }
        atomicMax(&s_maxd, (int)(m > 255u ? 255u : m));
    }

    // ---- histogram over key = level*8 + type ----
    for (int i = tid; i < 2049; i += 256) scanA[i] = 0;
    __syncthreads();
    for (int i = tid; i < NN; i += 256) {
        if (i >= NR) {
            unsigned lv = depth[i]; if (lv > 255u) lv = 255u;
            int key = (int)lv * 8 + gtyp[i];
            keys[i] = (unsigned short)key;
            atomicAdd(&scanA[key], 1u);
        }
    }
    __syncthreads();

    // ---- inclusive scan over 2048 buckets (11 Hillis-Steele rounds) ----
    {
        unsigned int* src = scanA;
        unsigned int* dst = scanB;
        for (int off = 1; off < 2048; off <<= 1) {
            for (int i = tid; i < 2048; i += 256) {
                unsigned v = src[i];
                if (i >= off) v += src[i - off];
                dst[i] = v;
            }
            __syncthreads();
            unsigned int* tmp = src; src = dst; dst = tmp;
        }
        // 11 rounds (odd) -> inclusive result is in scanB (src == scanB)
    }
    // exclusive offsets -> scanA (with sentinel)
    for (int i = tid; i < 2048; i += 256) scanA[i] = (i == 0) ? 0u : scanB[i - 1];
    if (tid == 0) scanA[2048] = scanB[2047];
    __syncthreads();
    // cursors -> scanB
    for (int i = tid; i < 2048; i += 256) scanB[i] = scanA[i];
    __syncthreads();

    // ---- scatter nodes into list, sorted by key ----
    for (int i = tid; i < NN; i += 256) {
        if (i >= NR) {
            unsigned pos = atomicAdd(&scanB[keys[i]], 1u);
            list[pos] = (unsigned short)i;
        }
    }
    __syncthreads();

    // ---- execute levels ----
    const int w    = tid >> 6;
    const int lane = tid & 63;
    const int q    = lane >> 4;
    const int l    = lane & 15;
    const int maxd = s_maxd;

    for (int L = 1; L <= maxd; ++L) {
        #pragma unroll
        for (int ti = 0; ti < 2; ++ti) {
            const int t = w + ti * 4;
            const int key = L * 8 + t;
            const unsigned seg = scanA[key];
            const int cnt = (int)(scanA[key + 1] - seg);
            for (int r0 = 0; r0 < cnt; r0 += 16) {
                const int rows = min(16, cnt - r0);
                // ---- gather X[16,128] -> bf16 LDS ----
                #pragma unroll
                for (int r = 0; r < 16; ++r) {
                    const bool live = (r < rows);
                    const int node = list[seg + r0 + (live ? r : 0)];
                    const int2 p = gidx[node];
                    const float x0 = gbuf[p.x * 64 + lane];
                    const float x1 = gbuf[p.y * 64 + lane];
                    xs[w][r][lane]      = live ? f2bf(x0) : (unsigned short)0;
                    xs[w][r][64 + lane] = live ? f2bf(x1) : (unsigned short)0;
                }
                __threadfence_block();   // wave-local: drain ds_writes before cross-lane ds_reads

                // ---- layer 1: C1[16,128] = X * W1 ----
                f32x4 c1[8];
                #pragma unroll
                for (int n0 = 0; n0 < 8; ++n0) c1[n0] = (f32x4){0.f, 0.f, 0.f, 0.f};
                #pragma unroll
                for (int kk = 0; kk < 4; ++kk) {
                    const short8 a = *(const short8*)&xs[w][l][kk * 32 + q * 8];
                    #pragma unroll
                    for (int n0 = 0; n0 < 8; ++n0) {
                        const short8 bf = *(const short8*)(w1t +
                            ((size_t)(t * 128 + n0 * 16 + l) * 128 + kk * 32 + q * 8));
                        c1[n0] = __builtin_amdgcn_mfma_f32_16x16x32_bf16(a, bf, c1[n0], 0, 0, 0);
                    }
                }
                // ---- bias + GELU -> hs (bf16) ----
                #pragma unroll
                for (int n0 = 0; n0 < 8; ++n0) {
                    const float bv = b1[t * 128 + n0 * 16 + l];
                    #pragma unroll
                    for (int rg = 0; rg < 4; ++rg) {
                        const float v = c1[n0][rg] + bv;
                        const float g = 0.5f * v * (1.0f + erff(v * 0.70710678118654752f));
                        hs[w][q * 4 + rg][n0 * 16 + l] = f2bf(g);
                    }
                }
                __threadfence_block();

                // ---- layer 2: C2[16,64] = hs * W2 ----
                f32x4 c2[4];
                #pragma unroll
                for (int n0 = 0; n0 < 4; ++n0) c2[n0] = (f32x4){0.f, 0.f, 0.f, 0.f};
                #pragma unroll
                for (int kk = 0; kk < 4; ++kk) {
                    const short8 a2 = *(const short8*)&hs[w][l][kk * 32 + q * 8];
                    #pragma unroll
                    for (int n0 = 0; n0 < 4; ++n0) {
                        const short8 bf = *(const short8*)(w2t +
                            ((size_t)(t * 64 + n0 * 16 + l) * 128 + kk * 32 + q * 8));
                        c2[n0] = __builtin_amdgcn_mfma_f32_16x16x32_bf16(a2, bf, c2[n0], 0, 0, 0);
                    }
                }
                // ---- +b2, scatter store ----
                #pragma unroll
                for (int n0 = 0; n0 < 4; ++n0) {
                    const float bv = b2[t * 64 + n0 * 16 + l];
                    #pragma unroll
                    for (int rg = 0; rg < 4; ++rg) {
                        const int row = q * 4 + rg;
                        if (row < rows) {
                            const int node = list[seg + r0 + row];
                            gbuf[node * 64 + n0 * 16 + l] = c2[n0][rg] + bv;
                        }
                    }
                }
            }
        }
        __syncthreads();   // level boundary: outputs visible to all waves
    }
}

extern "C" void kernel_launch(void* const* d_in, const int* in_sizes, int n_in,
                              void* d_out, int out_size, void* d_ws, size_t ws_size,
                              hipStream_t stream) {
    const float* roots = (const float*)d_in[0];
    const float* W1    = (const float*)d_in[1];
    const float* b1    = (const float*)d_in[2];
    const float* W2    = (const float*)d_in[3];
    const float* b2    = (const float*)d_in[4];
    const int*   idxs  = (const int*)d_in[5];
    const int*   types = (const int*)d_in[6];
    float*       outp  = (float*)d_out;

    unsigned short* w1t = (unsigned short*)d_ws;        // 8*128*128*2 = 256 KB
    unsigned short* w2t = w1t + NT * 128 * 128;         // 8*64*128*2  = 128 KB

    convert_weights<<<dim3(512), dim3(256), 0, stream>>>(W1, W2, w1t, w2t);
    dag_encoder_kernel<<<dim3(NB), dim3(256), 0, stream>>>(
        roots, b1, b2, idxs, types, outp, w1t, w2t);
}

// Round 4
// 543.765 us; speedup vs baseline: 7.6759x; 1.9507x over previous
//
#include <hip/hip_runtime.h>
#include <hip/hip_bf16.h>
#include <math.h>

// Problem constants
#define NB 256   // graphs
#define NN 2048  // nodes
#define NR 64    // roots
#define ND 64    // embed dim
#define NT 8     // node types
#define NTH 768  // threads per block (12 waves)
#define NW 12    // waves per block
#define XP 136   // xs/hs row stride in shorts (272 B: 16B-aligned rows, conflict-benign)

typedef __attribute__((ext_vector_type(8))) short short8;
typedef __attribute__((ext_vector_type(4))) float f32x4;

__device__ __forceinline__ unsigned short f2bf(float f) {
    unsigned u = __float_as_uint(f);
    return (unsigned short)((u + 0x7fffu + ((u >> 16) & 1u)) >> 16);
}

// ---------------------------------------------------------------------------
// Pre-kernel: transpose weights to [type][out][in] bf16 (RNE).
// ---------------------------------------------------------------------------
__global__ void convert_weights(const float* __restrict__ W1,
                                const float* __restrict__ W2,
                                unsigned short* __restrict__ w1t,
                                unsigned short* __restrict__ w2t) {
    int g = blockIdx.x * 256 + threadIdx.x;
    if (g < NT * 128 * 128) {
        int t = g >> 14, r = g & 16383, j = r >> 7, i = r & 127;
        w1t[g] = f2bf(W1[(t * 128 + i) * 128 + j]);
    }
    if (g < NT * 64 * 128) {
        int t = g >> 13, r = g & 8191, d = r >> 7, jj = r & 127;
        w2t[g] = f2bf(W2[(t * 128 + jj) * 64 + d]);
    }
}

// ---------------------------------------------------------------------------
// One block (768 thr, 12 waves) per graph.
// Prep: depth relaxation -> counting sort by key=(level*8+type) -> tile
//       descriptor list per level.
// Exec: per level, waves pull 16-row MFMA tiles from an LDS work queue.
// ---------------------------------------------------------------------------
__global__ __launch_bounds__(NTH, 1)
void dag_encoder_kernel(const float* __restrict__ roots,
                        const float* __restrict__ b1,
                        const float* __restrict__ b2,
                        const int*   __restrict__ idxs,
                        const int*   __restrict__ types,
                        float* __restrict__ out,
                        const unsigned short* __restrict__ w1t,
                        const unsigned short* __restrict__ w2t)
{
    __shared__ unsigned int   depth[NN];        // 8 KB  (later: scatter cursors, scan2 ping)
    __shared__ unsigned short keys[NN];         // 4 KB
    __shared__ unsigned int   scanA[NN + 1];    // 8.2 KB (final: exclusive key offsets)
    __shared__ unsigned int   scanB[NN + 1];    // 8.2 KB (scan scratch; final: incl. tile scan)
    __shared__ unsigned short list[NN];         // 4 KB  (nodes sorted by key)
    __shared__ unsigned short parv[2 * NN];     // 8 KB  (parent indices)
    __shared__ int            tiles[NN];        // 8 KB  (tile descriptors)
    __shared__ unsigned int   levT[258];        // per-level tile range
    __shared__ unsigned int   cursors[256];     // per-level work-queue cursor
    __shared__ __align__(16) unsigned short xs[NW][16][XP];  // 51 KB
    __shared__ __align__(16) unsigned short hs[NW][16][XP];  // 51 KB
    __shared__ int s_changed, s_maxd;

    const int b    = blockIdx.x;
    const int tid  = threadIdx.x;
    const int w    = tid >> 6;
    const int lane = tid & 63;
    const int q    = lane >> 4;
    const int l    = lane & 15;

    float* gbuf = out + (size_t)b * NN * ND;
    const int* gtyp = types + (size_t)b * NN;
    const int* gi   = idxs  + (size_t)b * NN * 2;

    // ---- roots -> gbuf; parents -> LDS; depth init ----
    {
        const float4* r4 = (const float4*)(roots + (size_t)b * NR * ND);
        float4* o4 = (float4*)gbuf;
        for (int i = tid; i < NR * ND / 4; i += NTH) o4[i] = r4[i];
        for (int i = tid; i < 2 * NN; i += NTH) parv[i] = (unsigned short)gi[i];
        for (int i = tid; i < NN; i += NTH) depth[i] = (i < NR) ? 0u : 0xFFFFFFFFu;
        for (int i = tid; i < 256; i += NTH) cursors[i] = 0;
        if (tid == 0) s_maxd = 0;
    }
    __syncthreads();

    // ---- depth relaxation: in-order chunk sweeps to fixed point ----
    for (int sweep = 0; sweep < NN; ++sweep) {
        if (tid == 0) s_changed = 0;
        __syncthreads();
        #pragma unroll
        for (int c = 0; c < 3; ++c) {
            int n = c * NTH + tid;
            if (n >= NR && n < NN && depth[n] == 0xFFFFFFFFu) {
                unsigned d0 = depth[parv[2 * n]];
                unsigned d1 = depth[parv[2 * n + 1]];
                if (d0 != 0xFFFFFFFFu && d1 != 0xFFFFFFFFu) {
                    depth[n] = 1u + (d0 > d1 ? d0 : d1);
                    s_changed = 1;
                }
            }
            __syncthreads();
        }
        bool done = (s_changed == 0);
        __syncthreads();
        if (done) break;
    }

    // ---- keys + histogram + maxd ----
    for (int i = tid; i <= NN; i += NTH) scanA[i] = 0;
    __syncthreads();
    {
        unsigned mloc = 0;
        for (int i = tid; i < NN; i += NTH) {
            if (i >= NR) {
                unsigned lv = depth[i]; if (lv > 255u) lv = 255u;
                if (lv > mloc) mloc = lv;
                int key = (int)lv * 8 + gtyp[i];
                keys[i] = (unsigned short)key;
                atomicAdd(&scanA[key], 1u);
            }
        }
        atomicMax(&s_maxd, (int)mloc);
    }
    __syncthreads();

    // ---- scan1: inclusive scan of bucket counts -> scanB ----
    {
        unsigned int* src = scanA;
        unsigned int* dst = scanB;
        for (int off = 1; off < NN; off <<= 1) {   // 11 rounds (odd -> ends in scanB)
            for (int i = tid; i < NN; i += NTH) {
                unsigned v = src[i];
                if (i >= off) v += src[i - off];
                dst[i] = v;
            }
            __syncthreads();
            unsigned int* tmp = src; src = dst; dst = tmp;
        }
    }
    // exclusive offsets -> scanA (+ sentinel); cursors copy -> depth (dead)
    for (int i = tid; i < NN; i += NTH) scanA[i] = (i == 0) ? 0u : scanB[i - 1];
    if (tid == 0) scanA[NN] = scanB[NN - 1];
    __syncthreads();
    for (int i = tid; i < NN; i += NTH) depth[i] = scanA[i];
    __syncthreads();

    // ---- scatter nodes into list (sorted by key) ----
    for (int i = tid; i < NN; i += NTH) {
        if (i >= NR) {
            unsigned p = atomicAdd(&depth[keys[i]], 1u);
            list[p] = (unsigned short)i;
        }
    }
    __syncthreads();

    // ---- tiles-per-key + scan2 (depth/scanB ping-pong, ends in scanB) ----
    for (int k = tid; k < NN; k += NTH) {
        unsigned cnt = scanA[k + 1] - scanA[k];
        depth[k] = (cnt + 15u) >> 4;
    }
    __syncthreads();
    {
        unsigned int* src = depth;
        unsigned int* dst = scanB;
        for (int off = 1; off < NN; off <<= 1) {
            for (int i = tid; i < NN; i += NTH) {
                unsigned v = src[i];
                if (i >= off) v += src[i - off];
                dst[i] = v;
            }
            __syncthreads();
            unsigned int* tmp = src; src = dst; dst = tmp;
        }
    }
    // tile descriptors + per-level ranges
    for (int k = tid; k < NN; k += NTH) {
        unsigned base = (k == 0) ? 0u : scanB[k - 1];
        unsigned nt   = scanB[k] - base;
        for (unsigned ti = 0; ti < nt; ++ti)
            tiles[base + ti] = (k << 8) | (int)ti;
    }
    for (int L = tid; L <= 256; L += NTH)
        levT[L] = (L == 0) ? 0u : scanB[8 * L - 1];
    __syncthreads();

    // ---- execute levels with per-level work queue ----
    const int maxd = s_maxd;
    for (int L = 1; L <= maxd; ++L) {
        const unsigned t0 = levT[L], t1 = levT[L + 1];
        while (true) {
            int my = 0;
            if (lane == 0) my = (int)atomicAdd(&cursors[L], 1u);
            my = __shfl(my, 0, 64);
            const unsigned ti = t0 + (unsigned)my;
            if (ti >= t1) break;

            const int desc = tiles[ti];
            const int key  = desc >> 8;
            const int r0   = (desc & 255) << 4;
            const int t    = key & 7;
            const unsigned seg = scanA[key];
            const int rows = min(16, (int)(scanA[key + 1] - seg) - r0);

            // ---- gather X[16,128] -> bf16 LDS (float4 coalesced) ----
            #pragma unroll
            for (int it = 0; it < 8; ++it) {
                const int rp  = it * 4 + q;        // row-parent 0..31
                const int row = rp >> 1, par = rp & 1;
                const int rr  = min(row, rows - 1);
                const int node = list[seg + r0 + rr];
                const int p    = parv[2 * node + par];
                const float4 x = *(const float4*)(gbuf + p * 64 + l * 4);
                unsigned lo = (unsigned)f2bf(x.x) | ((unsigned)f2bf(x.y) << 16);
                unsigned hi = (unsigned)f2bf(x.z) | ((unsigned)f2bf(x.w) << 16);
                *(uint2*)&xs[w][row][par * 64 + l * 4] = make_uint2(lo, hi);
            }
            __threadfence_block();

            // ---- layer 1 (two 64-col halves to cap registers) ----
            short8 af[4];
            #pragma unroll
            for (int kk = 0; kk < 4; ++kk)
                af[kk] = *(const short8*)&xs[w][l][kk * 32 + q * 8];

            #pragma unroll
            for (int h = 0; h < 2; ++h) {
                f32x4 c1[4];
                float bv[4];
                #pragma unroll
                for (int n0 = 0; n0 < 4; ++n0) {
                    c1[n0] = (f32x4){0.f, 0.f, 0.f, 0.f};
                    bv[n0] = b1[t * 128 + (h * 4 + n0) * 16 + l];
                }
                #pragma unroll
                for (int kk = 0; kk < 4; ++kk) {
                    #pragma unroll
                    for (int n0 = 0; n0 < 4; ++n0) {
                        const short8 bf = *(const short8*)(w1t +
                            ((size_t)(t * 128 + (h * 4 + n0) * 16 + l) * 128 + kk * 32 + q * 8));
                        c1[n0] = __builtin_amdgcn_mfma_f32_16x16x32_bf16(af[kk], bf, c1[n0], 0, 0, 0);
                    }
                }
                #pragma unroll
                for (int n0 = 0; n0 < 4; ++n0) {
                    #pragma unroll
                    for (int rg = 0; rg < 4; ++rg) {
                        const float v = c1[n0][rg] + bv[n0];
                        const float g = 0.5f * v * (1.0f + erff(v * 0.70710678118654752f));
                        hs[w][q * 4 + rg][(h * 4 + n0) * 16 + l] = f2bf(g);
                    }
                }
            }
            __threadfence_block();

            // ---- layer 2 ----
            short8 a2[4];
            #pragma unroll
            for (int kk = 0; kk < 4; ++kk)
                a2[kk] = *(const short8*)&hs[w][l][kk * 32 + q * 8];
            f32x4 c2[4];
            float bv2[4];
            #pragma unroll
            for (int n0 = 0; n0 < 4; ++n0) {
                c2[n0] = (f32x4){0.f, 0.f, 0.f, 0.f};
                bv2[n0] = b2[t * 64 + n0 * 16 + l];
            }
            #pragma unroll
            for (int kk = 0; kk < 4; ++kk) {
                #pragma unroll
                for (int n0 = 0; n0 < 4; ++n0) {
                    const short8 bf = *(const short8*)(w2t +
                        ((size_t)(t * 64 + n0 * 16 + l) * 128 + kk * 32 + q * 8));
                    c2[n0] = __builtin_amdgcn_mfma_f32_16x16x32_bf16(a2[kk], bf, c2[n0], 0, 0, 0);
                }
            }
            // ---- epilogue: +b2, scatter store ----
            #pragma unroll
            for (int rg = 0; rg < 4; ++rg) {
                const int row = q * 4 + rg;
                if (row < rows) {
                    const int node = list[seg + r0 + row];
                    float* gp = gbuf + node * 64 + l;
                    #pragma unroll
                    for (int n0 = 0; n0 < 4; ++n0)
                        gp[n0 * 16] = c2[n0][rg] + bv2[n0];
                }
            }
        }
        __syncthreads();   // level boundary
    }
}

extern "C" void kernel_launch(void* const* d_in, const int* in_sizes, int n_in,
                              void* d_out, int out_size, void* d_ws, size_t ws_size,
                              hipStream_t stream) {
    const float* roots = (const float*)d_in[0];
    const float* W1    = (const float*)d_in[1];
    const float* b1    = (const float*)d_in[2];
    const float* W2    = (const float*)d_in[3];
    const float* b2    = (const float*)d_in[4];
    const int*   idxs  = (const int*)d_in[5];
    const int*   types = (const int*)d_in[6];
    float*       outp  = (float*)d_out;

    unsigned short* w1t = (unsigned short*)d_ws;        // 256 KB
    unsigned short* w2t = w1t + NT * 128 * 128;         // 128 KB

    convert_weights<<<dim3(512), dim3(256), 0, stream>>>(W1, W2, w1t, w2t);
    dag_encoder_kernel<<<dim3(NB), dim3(NTH), 0, stream>>>(
        roots, b1, b2, idxs, types, outp, w1t, w2t);
}